// Round 1
// baseline (533.993 us; speedup 1.0000x reference)
//
#include <hip/hip_runtime.h>
#include <hip/hip_bf16.h>
#include <stdint.h>

#define SEQ   2048
#define DM    1024
#define NH    16
#define DKH   64
#define MTOK  8192   // 4*2048

typedef __attribute__((ext_vector_type(8)))  short         short8;
typedef __attribute__((ext_vector_type(4)))  unsigned short us4;
typedef __attribute__((ext_vector_type(4)))  float         f32x4;
typedef __attribute__((ext_vector_type(16))) float         f32x16;

__device__ __forceinline__ unsigned short f2bf(float f) {
    union { float f; uint32_t u; } v; v.f = f;
    return (unsigned short)((v.u + 0x7FFFu + ((v.u >> 16) & 1u)) >> 16);
}

__device__ __forceinline__ void gld_lds16(const void* g, void* l) {
    __builtin_amdgcn_global_load_lds(
        (const __attribute__((address_space(1))) void*)g,
        (__attribute__((address_space(3))) void*)l, 16, 0, 0);
}

// ---------------- conversion / packing ----------------

__global__ void k_cvt_x(const float* __restrict__ x, unsigned short* __restrict__ xb) {
    int i = (blockIdx.x * blockDim.x + threadIdx.x) * 4;
    float4 v = *(const float4*)(x + i);
    us4 p; p[0] = f2bf(v.x); p[1] = f2bf(v.y); p[2] = f2bf(v.z); p[3] = f2bf(v.w);
    *(us4*)(xb + i) = p;
}

__global__ void k_pack_w(const float* __restrict__ wq, const float* __restrict__ wk,
                         const float* __restrict__ wv, const float* __restrict__ wo,
                         unsigned short* __restrict__ Wcat, unsigned short* __restrict__ Wob) {
    const int WSZ = 1024 * 1024;
    int i = (blockIdx.x * blockDim.x + threadIdx.x) * 4;  // 0 .. 4M-4
    const float* src; unsigned short* dst; int off;
    if (i < 3 * WSZ) {
        if (i < WSZ)            { src = wq; off = i; }
        else if (i < 2 * WSZ)   { src = wk; off = i - WSZ; }
        else                    { src = wv; off = i - 2 * WSZ; }
        dst = Wcat + i;
    } else {
        src = wo; off = i - 3 * WSZ; dst = Wob + off;
    }
    float4 v = *(const float4*)(src + off);
    us4 p; p[0] = f2bf(v.x); p[1] = f2bf(v.y); p[2] = f2bf(v.z); p[3] = f2bf(v.w);
    *(us4*)dst = p;
}

__global__ void k_pack_b(const float* __restrict__ bq, const float* __restrict__ bk,
                         const float* __restrict__ bv, float* __restrict__ Bcat) {
    int i = blockIdx.x * blockDim.x + threadIdx.x;  // < 3072
    float v = (i < 1024) ? bq[i] : (i < 2048 ? bk[i - 1024] : bv[i - 2048]);
    Bcat[i] = v;
}

// ---------------- GEMM: C[M,N] = A[M,K] * B[N,K]^T, m97-style ----------------
// EPI 0: QKV epilogue (scatter to Qb/Kb [bh][s][64] and Vt [bh][64][s], +bias, ->bf16)
// EPI 1: out = acc + bias -> fp32 d_out
template<int EPI>
__global__ __launch_bounds__(256)
void k_gemm(const unsigned short* __restrict__ A, const unsigned short* __restrict__ B,
            const float* __restrict__ bias, float* __restrict__ OutF,
            unsigned short* __restrict__ Qb, unsigned short* __restrict__ Kb,
            unsigned short* __restrict__ Vt, int Ntiles, int K) {
    __shared__ __align__(16) unsigned short As[128 * 64];
    __shared__ __align__(16) unsigned short Bs[128 * 64];
    const int t    = threadIdx.x;
    const int lane = t & 63;
    const int wid  = t >> 6;
    const int wm   = (wid >> 1) * 64, wn = (wid & 1) * 64;
    const int bn   = (blockIdx.x % Ntiles) * 128;
    const int bmr  = (blockIdx.x / Ntiles) * 128;
    const int sr   = t >> 3, sc = t & 7;      // staging row / 16B-chunk
    const int l15  = lane & 15, lh = lane >> 4;

    f32x4 acc[4][4];
#pragma unroll
    for (int i = 0; i < 4; ++i)
#pragma unroll
        for (int j = 0; j < 4; ++j)
#pragma unroll
            for (int e = 0; e < 4; ++e) acc[i][j][e] = 0.f;

    for (int k0 = 0; k0 < K; k0 += 64) {
#pragma unroll
        for (int i = 0; i < 4; ++i) {   // stage A tile (pre-swizzled source)
            int r = i * 32 + sr;
            int cs = sc ^ (r & 7);
            gld_lds16(A + ((size_t)(bmr + r) * K + k0 + cs * 8), As + (size_t)t * 8 + i * 2048);
        }
#pragma unroll
        for (int i = 0; i < 4; ++i) {   // stage B tile
            int r = i * 32 + sr;
            int cs = sc ^ (r & 7);
            gld_lds16(B + ((size_t)(bn + r) * K + k0 + cs * 8), Bs + (size_t)t * 8 + i * 2048);
        }
        __syncthreads();
#pragma unroll
        for (int kk = 0; kk < 64; kk += 32) {
            short8 af[4], bf[4];
#pragma unroll
            for (int mi = 0; mi < 4; ++mi) {
                int row = wm + mi * 16 + l15;
                int c = (kk >> 3) + lh;
                af[mi] = *(const short8*)(As + row * 64 + (c ^ (row & 7)) * 8);
            }
#pragma unroll
            for (int ni = 0; ni < 4; ++ni) {
                int row = wn + ni * 16 + l15;
                int c = (kk >> 3) + lh;
                bf[ni] = *(const short8*)(Bs + row * 64 + (c ^ (row & 7)) * 8);
            }
#pragma unroll
            for (int mi = 0; mi < 4; ++mi)
#pragma unroll
                for (int ni = 0; ni < 4; ++ni)
                    acc[mi][ni] = __builtin_amdgcn_mfma_f32_16x16x32_bf16(
                        af[mi], bf[ni], acc[mi][ni], 0, 0, 0);
        }
        __syncthreads();
    }

#pragma unroll
    for (int mi = 0; mi < 4; ++mi)
#pragma unroll
        for (int ni = 0; ni < 4; ++ni) {
            int n  = bn + wn + ni * 16 + l15;
            int m0 = bmr + wm + mi * 16 + lh * 4;
            float bv = bias[n];
            if constexpr (EPI == 0) {
                int proj = n >> 10;
                int e = n & 1023;
                int hh = e >> 6, dk = e & 63;
                int b = m0 >> 11, s = m0 & 2047;
                int bh = b * NH + hh;
                if (proj == 2) {          // V -> transposed [bh][dk][s], 8B packed
                    us4 p;
#pragma unroll
                    for (int j = 0; j < 4; ++j) p[j] = f2bf(acc[mi][ni][j] + bv);
                    *(us4*)(Vt + (size_t)(bh * DKH + dk) * SEQ + s) = p;
                } else {                  // Q/K -> [bh][s][64]
                    unsigned short* dst = (proj == 0) ? Qb : Kb;
#pragma unroll
                    for (int j = 0; j < 4; ++j)
                        dst[((size_t)bh * SEQ + s + j) * DKH + dk] = f2bf(acc[mi][ni][j] + bv);
                }
            } else {
#pragma unroll
                for (int j = 0; j < 4; ++j)
                    OutF[(size_t)(m0 + j) * DM + n] = acc[mi][ni][j] + bv;
            }
        }
}

// ---------------- flash attention, 32x32x16 bf16, swapped QK^T ----------------
// grid: [bh(64) * qtile(16)], 256 threads = 4 waves, each wave owns 32 q-rows.
__global__ __launch_bounds__(256)
void k_attn(const unsigned short* __restrict__ Qb, const unsigned short* __restrict__ Kb,
            const unsigned short* __restrict__ Vt, unsigned short* __restrict__ Ob) {
    const int t = threadIdx.x;
    const int lane = t & 63, w = t >> 6;
    const int bh = blockIdx.x >> 4;
    const int qt = blockIdx.x & 15;
    const int q0 = qt * 128 + w * 32;
    const int l31 = lane & 31, hi = lane >> 5;

    const unsigned short* Qp = Qb + (size_t)bh * SEQ * DKH;
    const unsigned short* Kp = Kb + (size_t)bh * SEQ * DKH;
    const unsigned short* Vp = Vt + (size_t)bh * DKH * SEQ;

    short8 qf[4];
#pragma unroll
    for (int c = 0; c < 4; ++c)
        qf[c] = *(const short8*)(Qp + (size_t)(q0 + l31) * DKH + c * 16 + hi * 8);

    f32x16 o0, o1;
#pragma unroll
    for (int j = 0; j < 16; ++j) { o0[j] = 0.f; o1[j] = 0.f; }
    float mrun = -1e30f, lrun = 0.f;
    const float SC = 0.125f * 1.44269504f;  // 1/sqrt(64) * log2(e)

    for (int kt = 0; kt < SEQ; kt += 32) {
        // S^T[32k x 32q] = K * Q^T ; contiguous-8 k-assumption cancels (same on A and B)
        f32x16 st;
#pragma unroll
        for (int j = 0; j < 16; ++j) st[j] = 0.f;
#pragma unroll
        for (int c = 0; c < 4; ++c) {
            short8 kf = *(const short8*)(Kp + (size_t)(kt + l31) * DKH + c * 16 + hi * 8);
            st = __builtin_amdgcn_mfma_f32_32x32x16_bf16(kf, qf[c], st, 0, 0, 0);
        }
        // online softmax, per-lane q = l31; keys split across lane^32
        float s[16]; float pm = -1e30f;
#pragma unroll
        for (int j = 0; j < 16; ++j) { s[j] = st[j] * SC; pm = fmaxf(pm, s[j]); }
        pm = fmaxf(pm, __shfl_xor(pm, 32));
        float mnew = fmaxf(mrun, pm);
        float fac = exp2f(mrun - mnew);
        float rs = 0.f;
        short8 p0, p1;
#pragma unroll
        for (int j = 0; j < 16; ++j) {
            float p = exp2f(s[j] - mnew);
            rs += p;
            unsigned short pb = f2bf(p);
            if (j < 8) p0[j] = (short)pb; else p1[j - 8] = (short)pb;
        }
        rs += __shfl_xor(rs, 32);
        lrun = lrun * fac + rs;
        mrun = mnew;
#pragma unroll
        for (int j = 0; j < 16; ++j) { o0[j] *= fac; o1[j] *= fac; }
        // PV: O^T[d,q] += V^T[d,key] * P^T[key,q]; P^T frag feeds B directly (crow layout)
#pragma unroll
        for (int dh = 0; dh < 2; ++dh) {
#pragma unroll
            for (int h = 0; h < 2; ++h) {
                size_t vrow = (size_t)(dh * 32 + l31) * SEQ + kt + h * 16 + hi * 4;
                us4 v0 = *(const us4*)(Vp + vrow);
                us4 v1 = *(const us4*)(Vp + vrow + 8);
                short8 vf;
#pragma unroll
                for (int j = 0; j < 4; ++j) { vf[j] = (short)v0[j]; vf[4 + j] = (short)v1[j]; }
                if (dh == 0) o0 = __builtin_amdgcn_mfma_f32_32x32x16_bf16(vf, (h ? p1 : p0), o0, 0, 0, 0);
                else         o1 = __builtin_amdgcn_mfma_f32_32x32x16_bf16(vf, (h ? p1 : p0), o1, 0, 0, 0);
            }
        }
    }

    float inv = 1.f / lrun;
    const int b = bh >> 4, hh = bh & 15;
    size_t tok = (size_t)b * SEQ + q0 + l31;
    unsigned short* Op = Ob + tok * DM + hh * DKH;
#pragma unroll
    for (int dh = 0; dh < 2; ++dh) {
#pragma unroll
        for (int g = 0; g < 4; ++g) {
            int d0 = 8 * g + 4 * hi + 32 * dh;
            us4 p;
#pragma unroll
            for (int j = 0; j < 4; ++j) {
                float v = (dh == 0) ? o0[4 * g + j] : o1[4 * g + j];
                p[j] = f2bf(v * inv);
            }
            *(us4*)(Op + d0) = p;
        }
    }
}

// ---------------- launch ----------------

extern "C" void kernel_launch(void* const* d_in, const int* in_sizes, int n_in,
                              void* d_out, int out_size, void* d_ws, size_t ws_size,
                              hipStream_t stream) {
    const float* x  = (const float*)d_in[0];
    const float* wq = (const float*)d_in[1];
    const float* bq = (const float*)d_in[2];
    const float* wk = (const float*)d_in[3];
    const float* bk = (const float*)d_in[4];
    const float* wv = (const float*)d_in[5];
    const float* bv = (const float*)d_in[6];
    const float* wo = (const float*)d_in[7];
    const float* bo = (const float*)d_in[8];

    char* ws = (char*)d_ws;
    // offsets (bytes). Ob aliases xb (xb dead after QKV GEMM).
    unsigned short* xb   = (unsigned short*)(ws + 0);             // 16 MB
    unsigned short* Wcat = (unsigned short*)(ws + 16777216);      // 6 MB
    unsigned short* Wob  = (unsigned short*)(ws + 23068672);      // 2 MB
    float*          Bcat = (float*)         (ws + 25165824);      // 16 KB pad
    unsigned short* Qb   = (unsigned short*)(ws + 25182208);      // 16 MB
    unsigned short* Kb   = (unsigned short*)(ws + 41959424);      // 16 MB
    unsigned short* Vt   = (unsigned short*)(ws + 58736640);      // 16 MB (total ~72 MB)
    unsigned short* Ob   = xb;

    k_cvt_x <<<MTOK * DM / 1024, 256, 0, stream>>>(x, xb);
    k_pack_w<<<4 * 1024 * 1024 / 1024, 256, 0, stream>>>(wq, wk, wv, wo, Wcat, Wob);
    k_pack_b<<<12, 256, 0, stream>>>(bq, bk, bv, Bcat);
    // QKV: M=8192 (64 tiles), N=3072 (24 tiles), K=1024
    k_gemm<0><<<64 * 24, 256, 0, stream>>>(xb, Wcat, Bcat, nullptr, Qb, Kb, Vt, 24, DM);
    // attention
    k_attn<<<64 * 16, 256, 0, stream>>>(Qb, Kb, Vt, Ob);
    // out projection: M=8192, N=1024 (8 tiles), K=1024 -> fp32 d_out
    k_gemm<1><<<64 * 8, 256, 0, stream>>>(Ob, Wob, bo, (float*)d_out, nullptr, nullptr, nullptr, 8, DM);
}

// Round 5
// 475.317 us; speedup vs baseline: 1.1234x; 1.1234x over previous
//
#include <hip/hip_runtime.h>
#include <hip/hip_bf16.h>
#include <stdint.h>

#define SEQ   2048
#define DM    1024
#define NH    16
#define DKH   64
#define MTOK  8192   // 4*2048

typedef __attribute__((ext_vector_type(8)))  short         short8;
typedef __attribute__((ext_vector_type(4)))  unsigned short us4;
typedef __attribute__((ext_vector_type(4)))  float         f32x4;
typedef __attribute__((ext_vector_type(16))) float         f32x16;

__device__ __forceinline__ unsigned short f2bf(float f) {
    union { float f; uint32_t u; } v; v.f = f;
    return (unsigned short)((v.u + 0x7FFFu + ((v.u >> 16) & 1u)) >> 16);
}

__device__ __forceinline__ unsigned short bfr(float f) {
    __hip_bfloat16 h = __float2bfloat16(f);
    return *reinterpret_cast<unsigned short*>(&h);
}

__device__ __forceinline__ float vmax16(f32x16 v) {
    float a = fmaxf(fmaxf(v[0], v[1]),  fmaxf(v[2], v[3]));
    float b = fmaxf(fmaxf(v[4], v[5]),  fmaxf(v[6], v[7]));
    float c = fmaxf(fmaxf(v[8], v[9]),  fmaxf(v[10], v[11]));
    float d = fmaxf(fmaxf(v[12], v[13]), fmaxf(v[14], v[15]));
    return fmaxf(fmaxf(a, b), fmaxf(c, d));
}

__device__ __forceinline__ void gld_lds16(const void* g, void* l) {
    __builtin_amdgcn_global_load_lds(
        (const __attribute__((address_space(1))) void*)g,
        (__attribute__((address_space(3))) void*)l, 16, 0, 0);
}

// ---------------- conversion / packing ----------------

__global__ void k_cvt_x(const float* __restrict__ x, unsigned short* __restrict__ xb) {
    int i = (blockIdx.x * blockDim.x + threadIdx.x) * 4;
    float4 v = *(const float4*)(x + i);
    us4 p; p[0] = f2bf(v.x); p[1] = f2bf(v.y); p[2] = f2bf(v.z); p[3] = f2bf(v.w);
    *(us4*)(xb + i) = p;
}

__global__ void k_pack_w(const float* __restrict__ wq, const float* __restrict__ wk,
                         const float* __restrict__ wv, const float* __restrict__ wo,
                         unsigned short* __restrict__ Wcat, unsigned short* __restrict__ Wob) {
    const int WSZ = 1024 * 1024;
    int i = (blockIdx.x * blockDim.x + threadIdx.x) * 4;  // 0 .. 4M-4
    const float* src; unsigned short* dst; int off;
    if (i < 3 * WSZ) {
        if (i < WSZ)            { src = wq; off = i; }
        else if (i < 2 * WSZ)   { src = wk; off = i - WSZ; }
        else                    { src = wv; off = i - 2 * WSZ; }
        dst = Wcat + i;
    } else {
        src = wo; off = i - 3 * WSZ; dst = Wob + off;
    }
    float4 v = *(const float4*)(src + off);
    us4 p; p[0] = f2bf(v.x); p[1] = f2bf(v.y); p[2] = f2bf(v.z); p[3] = f2bf(v.w);
    *(us4*)dst = p;
}

__global__ void k_pack_b(const float* __restrict__ bq, const float* __restrict__ bk,
                         const float* __restrict__ bv, float* __restrict__ Bcat) {
    int i = blockIdx.x * blockDim.x + threadIdx.x;  // < 3072
    float v = (i < 1024) ? bq[i] : (i < 2048 ? bk[i - 1024] : bv[i - 2048]);
    Bcat[i] = v;
}

// ---------------- GEMM: C[M,N] = A[M,K] * B[N,K]^T, m97-style ----------------
// EPI 0: QKV epilogue. Q: *QS (softmax scale folded, log2 domain), -> [bh][s][64]
//        K: -> [bh][s][64].  V: -> [bh][dk][key-permuted s] (swap bit2<->bit3 of s
//        so attention V fragments are single contiguous 16B loads).
// EPI 1: out = acc + bias -> fp32 d_out
template<int EPI>
__global__ __launch_bounds__(256)
void k_gemm(const unsigned short* __restrict__ A, const unsigned short* __restrict__ B,
            const float* __restrict__ bias, float* __restrict__ OutF,
            unsigned short* __restrict__ Qb, unsigned short* __restrict__ Kb,
            unsigned short* __restrict__ Vt, int Ntiles, int K) {
    __shared__ __align__(16) unsigned short As[128 * 64];
    __shared__ __align__(16) unsigned short Bs[128 * 64];
    const int t    = threadIdx.x;
    const int lane = t & 63;
    const int wid  = t >> 6;
    const int wm   = (wid >> 1) * 64, wn = (wid & 1) * 64;
    const int bn   = (blockIdx.x % Ntiles) * 128;
    const int bmr  = (blockIdx.x / Ntiles) * 128;
    const int sr   = t >> 3, sc = t & 7;      // staging row / 16B-chunk
    const int l15  = lane & 15, lh = lane >> 4;

    f32x4 acc[4][4];
#pragma unroll
    for (int i = 0; i < 4; ++i)
#pragma unroll
        for (int j = 0; j < 4; ++j)
#pragma unroll
            for (int e = 0; e < 4; ++e) acc[i][j][e] = 0.f;

    for (int k0 = 0; k0 < K; k0 += 64) {
#pragma unroll
        for (int i = 0; i < 4; ++i) {   // stage A tile (pre-swizzled source)
            int r = i * 32 + sr;
            int cs = sc ^ (r & 7);
            gld_lds16(A + ((size_t)(bmr + r) * K + k0 + cs * 8), As + (size_t)t * 8 + i * 2048);
        }
#pragma unroll
        for (int i = 0; i < 4; ++i) {   // stage B tile
            int r = i * 32 + sr;
            int cs = sc ^ (r & 7);
            gld_lds16(B + ((size_t)(bn + r) * K + k0 + cs * 8), Bs + (size_t)t * 8 + i * 2048);
        }
        __syncthreads();
#pragma unroll
        for (int kk = 0; kk < 64; kk += 32) {
            short8 af[4], bf[4];
#pragma unroll
            for (int mi = 0; mi < 4; ++mi) {
                int row = wm + mi * 16 + l15;
                int c = (kk >> 3) + lh;
                af[mi] = *(const short8*)(As + row * 64 + (c ^ (row & 7)) * 8);
            }
#pragma unroll
            for (int ni = 0; ni < 4; ++ni) {
                int row = wn + ni * 16 + l15;
                int c = (kk >> 3) + lh;
                bf[ni] = *(const short8*)(Bs + row * 64 + (c ^ (row & 7)) * 8);
            }
#pragma unroll
            for (int mi = 0; mi < 4; ++mi)
#pragma unroll
                for (int ni = 0; ni < 4; ++ni)
                    acc[mi][ni] = __builtin_amdgcn_mfma_f32_16x16x32_bf16(
                        af[mi], bf[ni], acc[mi][ni], 0, 0, 0);
        }
        __syncthreads();
    }

    const float QS = 0.180336880111f;   // (1/sqrt(64)) * log2(e)
#pragma unroll
    for (int mi = 0; mi < 4; ++mi)
#pragma unroll
        for (int ni = 0; ni < 4; ++ni) {
            int n  = bn + wn + ni * 16 + l15;
            int m0 = bmr + wm + mi * 16 + lh * 4;
            float bv = bias[n];
            if constexpr (EPI == 0) {
                int proj = n >> 10;
                int e = n & 1023;
                int hh = e >> 6, dk = e & 63;
                int b = m0 >> 11, s = m0 & 2047;
                int bh = b * NH + hh;
                if (proj == 2) {          // V -> [bh][dk][perm(s)], 8B packed
                    int sp = (s & ~12) | ((s & 4) << 1) | ((s & 8) >> 1);
                    us4 p;
#pragma unroll
                    for (int j = 0; j < 4; ++j) p[j] = f2bf(acc[mi][ni][j] + bv);
                    *(us4*)(Vt + (size_t)(bh * DKH + dk) * SEQ + sp) = p;
                } else {                  // Q/K -> [bh][s][64]; Q pre-scaled
                    unsigned short* dst = (proj == 0) ? Qb : Kb;
                    float sc = (proj == 0) ? QS : 1.f;
#pragma unroll
                    for (int j = 0; j < 4; ++j)
                        dst[((size_t)bh * SEQ + s + j) * DKH + dk] = f2bf((acc[mi][ni][j] + bv) * sc);
                }
            } else {
#pragma unroll
                for (int j = 0; j < 4; ++j)
                    OutF[(size_t)(m0 + j) * DM + n] = acc[mi][ni][j] + bv;
            }
        }
}

// ---------------- flash attention, 32x32x16 bf16, swapped QK^T, KVBLK=64 ----------------
// grid: 1024 blocks (XCD-chunked: 8 bh per XCD), 256 threads = 4 waves, 32 q-rows/wave.
// Q pre-scaled by (1/sqrt(dk))*log2e; running max folded into MFMA C-init (st = s - m);
// defer-max rescale (THR=8); V key-permuted so fragments load as contiguous 16B.
__global__ __launch_bounds__(256)
void k_attn(const unsigned short* __restrict__ Qb, const unsigned short* __restrict__ Kb,
            const unsigned short* __restrict__ Vt, unsigned short* __restrict__ Ob) {
    const int t = threadIdx.x;
    const int lane = t & 63, w = t >> 6;
    const int g = blockIdx.x;
    const int id = ((g & 7) << 7) | (g >> 3);   // XCD-chunked swizzle (bijective, 1024%8==0)
    const int bh = id >> 4;
    const int qt = id & 15;
    const int q0 = qt * 128 + w * 32;
    const int l31 = lane & 31, hi = lane >> 5;

    const unsigned short* Qp = Qb + (size_t)bh * SEQ * DKH;
    short8 qf[4];
#pragma unroll
    for (int c = 0; c < 4; ++c)
        qf[c] = *(const short8*)(Qp + (size_t)(q0 + l31) * DKH + c * 16 + hi * 8);

    f32x16 o0, o1;
#pragma unroll
    for (int j = 0; j < 16; ++j) { o0[j] = 0.f; o1[j] = 0.f; }
    float mr = 0.f, lr = 0.f;

    const unsigned short* pK0 = Kb + (size_t)bh * SEQ * DKH + l31 * DKH + hi * 8;
    const unsigned short* pK1 = pK0 + 32 * DKH;
    const unsigned short* pV0 = Vt + (size_t)bh * DKH * SEQ + l31 * SEQ + hi * 8;
    const unsigned short* pV1 = pV0 + 32 * SEQ;

    for (int kt = 0; kt < SEQ; kt += 64) {
        // S^T = K * Q^T with C-init = -m  (=> st holds s - m directly)
        f32x16 st0, st1;
        float nm = -mr;
#pragma unroll
        for (int j = 0; j < 16; ++j) { st0[j] = nm; st1[j] = nm; }
        __builtin_amdgcn_s_setprio(1);
#pragma unroll
        for (int c = 0; c < 4; ++c) {
            short8 kf = *(const short8*)(pK0 + c * 16);
            st0 = __builtin_amdgcn_mfma_f32_32x32x16_bf16(kf, qf[c], st0, 0, 0, 0);
        }
#pragma unroll
        for (int c = 0; c < 4; ++c) {
            short8 kf = *(const short8*)(pK1 + c * 16);
            st1 = __builtin_amdgcn_mfma_f32_32x32x16_bf16(kf, qf[c], st1, 0, 0, 0);
        }
        __builtin_amdgcn_s_setprio(0);
        // issue V loads early (consumed after softmax)
        short8 vf[8];
#pragma unroll
        for (int h = 0; h < 4; ++h) {
            vf[h]     = *(const short8*)(pV0 + h * 16);
            vf[4 + h] = *(const short8*)(pV1 + h * 16);
        }
        // online softmax in exp2 domain, per-lane q = l31 (pair across hi)
        float pm = fmaxf(vmax16(st0), vmax16(st1));
        pm = fmaxf(pm, __shfl_xor(pm, 32));
        if (__any(pm > 8.f)) {            // rare rescale path (defer-max)
            float d   = fmaxf(pm, 0.f);
            float fac = exp2f(-d);
            mr += d;
#pragma unroll
            for (int j = 0; j < 16; ++j) { st0[j] -= d; st1[j] -= d; }
#pragma unroll
            for (int j = 0; j < 16; ++j) { o0[j] *= fac; o1[j] *= fac; }
            lr *= fac;
        }
#pragma unroll
        for (int j = 0; j < 16; ++j) { st0[j] = exp2f(st0[j]); st1[j] = exp2f(st1[j]); }
        float r0 = 0.f, r1 = 0.f, r2 = 0.f, r3 = 0.f;
#pragma unroll
        for (int j = 0; j < 4; ++j) {
            r0 += st0[j] + st0[4 + j];
            r1 += st0[8 + j] + st0[12 + j];
            r2 += st1[j] + st1[4 + j];
            r3 += st1[8 + j] + st1[12 + j];
        }
        float rs = (r0 + r1) + (r2 + r3);
        rs += __shfl_xor(rs, 32);
        lr += rs;
        // pack P fragments (B-operand layout == C-frag reg order, 8 regs per 16-key group)
        short8 p[4];
#pragma unroll
        for (int j = 0; j < 8; ++j) {
            p[0][j] = (short)bfr(st0[j]);
            p[1][j] = (short)bfr(st0[8 + j]);
            p[2][j] = (short)bfr(st1[j]);
            p[3][j] = (short)bfr(st1[8 + j]);
        }
        // PV: O^T += V^T * P^T
        __builtin_amdgcn_s_setprio(1);
#pragma unroll
        for (int h = 0; h < 4; ++h)
            o0 = __builtin_amdgcn_mfma_f32_32x32x16_bf16(vf[h], p[h], o0, 0, 0, 0);
#pragma unroll
        for (int h = 0; h < 4; ++h)
            o1 = __builtin_amdgcn_mfma_f32_32x32x16_bf16(vf[4 + h], p[h], o1, 0, 0, 0);
        __builtin_amdgcn_s_setprio(0);
        pK0 += 64 * DKH; pK1 += 64 * DKH; pV0 += 64; pV1 += 64;
    }

    float inv = 1.f / lr;
    const int b = bh >> 4, hh = bh & 15;
    size_t tok = (size_t)b * SEQ + q0 + l31;
    unsigned short* Op = Ob + tok * DM + hh * DKH;
#pragma unroll
    for (int gi = 0; gi < 4; ++gi) {
        us4 pa, pb;
#pragma unroll
        for (int j = 0; j < 4; ++j) {
            pa[j] = bfr(o0[4 * gi + j] * inv);
            pb[j] = bfr(o1[4 * gi + j] * inv);
        }
        *(us4*)(Op + 8 * gi + 4 * hi)      = pa;
        *(us4*)(Op + 8 * gi + 4 * hi + 32) = pb;
    }
}

// ---------------- launch ----------------

extern "C" void kernel_launch(void* const* d_in, const int* in_sizes, int n_in,
                              void* d_out, int out_size, void* d_ws, size_t ws_size,
                              hipStream_t stream) {
    const float* x  = (const float*)d_in[0];
    const float* wq = (const float*)d_in[1];
    const float* bq = (const float*)d_in[2];
    const float* wk = (const float*)d_in[3];
    const float* bk = (const float*)d_in[4];
    const float* wv = (const float*)d_in[5];
    const float* bv = (const float*)d_in[6];
    const float* wo = (const float*)d_in[7];
    const float* bo = (const float*)d_in[8];

    char* ws = (char*)d_ws;
    // offsets (bytes). Ob aliases xb (xb dead after QKV GEMM).
    unsigned short* xb   = (unsigned short*)(ws + 0);             // 16 MB
    unsigned short* Wcat = (unsigned short*)(ws + 16777216);      // 6 MB
    unsigned short* Wob  = (unsigned short*)(ws + 23068672);      // 2 MB
    float*          Bcat = (float*)         (ws + 25165824);      // 16 KB pad
    unsigned short* Qb   = (unsigned short*)(ws + 25182208);      // 16 MB
    unsigned short* Kb   = (unsigned short*)(ws + 41959424);      // 16 MB
    unsigned short* Vt   = (unsigned short*)(ws + 58736640);      // 16 MB (total ~72 MB)
    unsigned short* Ob   = xb;

    k_cvt_x <<<MTOK * DM / 1024, 256, 0, stream>>>(x, xb);
    k_pack_w<<<4 * 1024 * 1024 / 1024, 256, 0, stream>>>(wq, wk, wv, wo, Wcat, Wob);
    k_pack_b<<<12, 256, 0, stream>>>(bq, bk, bv, Bcat);
    // QKV: M=8192 (64 tiles), N=3072 (24 tiles), K=1024
    k_gemm<0><<<64 * 24, 256, 0, stream>>>(xb, Wcat, Bcat, nullptr, Qb, Kb, Vt, 24, DM);
    // attention
    k_attn<<<64 * 16, 256, 0, stream>>>(Qb, Kb, Vt, Ob);
    // out projection: M=8192, N=1024 (8 tiles), K=1024 -> fp32 d_out
    k_gemm<1><<<64 * 8, 256, 0, stream>>>(Ob, Wob, bo, (float*)d_out, nullptr, nullptr, nullptr, 8, DM);
}

// Round 7
// 328.914 us; speedup vs baseline: 1.6235x; 1.4451x over previous
//
#include <hip/hip_runtime.h>
#include <hip/hip_bf16.h>
#include <stdint.h>

#define SEQ   2048
#define DM    1024
#define NH    16
#define DKH   64
#define MTOK  8192   // 4*2048

typedef __attribute__((ext_vector_type(8)))  short         short8;
typedef __attribute__((ext_vector_type(4)))  unsigned short us4;
typedef __attribute__((ext_vector_type(4)))  float         f32x4;
typedef __attribute__((ext_vector_type(16))) float         f32x16;

__device__ __forceinline__ unsigned short f2bf(float f) {
    union { float f; uint32_t u; } v; v.f = f;
    return (unsigned short)((v.u + 0x7FFFu + ((v.u >> 16) & 1u)) >> 16);
}

__device__ __forceinline__ unsigned short bfr(float f) {
    __hip_bfloat16 h = __float2bfloat16(f);
    return *reinterpret_cast<unsigned short*>(&h);
}

__device__ __forceinline__ float vmax16(f32x16 v) {
    float a = fmaxf(fmaxf(v[0], v[1]),  fmaxf(v[2], v[3]));
    float b = fmaxf(fmaxf(v[4], v[5]),  fmaxf(v[6], v[7]));
    float c = fmaxf(fmaxf(v[8], v[9]),  fmaxf(v[10], v[11]));
    float d = fmaxf(fmaxf(v[12], v[13]), fmaxf(v[14], v[15]));
    return fmaxf(fmaxf(a, b), fmaxf(c, d));
}

__device__ __forceinline__ void gld_lds16(const void* g, void* l) {
    __builtin_amdgcn_global_load_lds(
        (const __attribute__((address_space(1))) void*)g,
        (__attribute__((address_space(3))) void*)l, 16, 0, 0);
}

// ---------------- conversion / packing ----------------

__global__ void k_cvt_x(const float* __restrict__ x, unsigned short* __restrict__ xb) {
    int i = (blockIdx.x * blockDim.x + threadIdx.x) * 4;
    float4 v = *(const float4*)(x + i);
    us4 p; p[0] = f2bf(v.x); p[1] = f2bf(v.y); p[2] = f2bf(v.z); p[3] = f2bf(v.w);
    *(us4*)(xb + i) = p;
}

__global__ void k_pack_w(const float* __restrict__ wq, const float* __restrict__ wk,
                         const float* __restrict__ wv, const float* __restrict__ wo,
                         unsigned short* __restrict__ Wcat, unsigned short* __restrict__ Wob) {
    const int WSZ = 1024 * 1024;
    int i = (blockIdx.x * blockDim.x + threadIdx.x) * 4;  // 0 .. 4M-4
    const float* src; unsigned short* dst; int off;
    if (i < 3 * WSZ) {
        if (i < WSZ)            { src = wq; off = i; }
        else if (i < 2 * WSZ)   { src = wk; off = i - WSZ; }
        else                    { src = wv; off = i - 2 * WSZ; }
        dst = Wcat + i;
    } else {
        src = wo; off = i - 3 * WSZ; dst = Wob + off;
    }
    float4 v = *(const float4*)(src + off);
    us4 p; p[0] = f2bf(v.x); p[1] = f2bf(v.y); p[2] = f2bf(v.z); p[3] = f2bf(v.w);
    *(us4*)dst = p;
}

__global__ void k_pack_b(const float* __restrict__ bq, const float* __restrict__ bk,
                         const float* __restrict__ bv, float* __restrict__ Bcat) {
    int i = blockIdx.x * blockDim.x + threadIdx.x;  // < 3072
    float v = (i < 1024) ? bq[i] : (i < 2048 ? bk[i - 1024] : bv[i - 2048]);
    Bcat[i] = v;
}

// ---------------- GEMM: C[M,N] = A[M,K] * B[N,K]^T, m97-style ----------------
// EPI 0: QKV epilogue. Q: *QS (softmax scale folded, log2 domain), -> [bh][s][64]
//        K: -> [bh][s][64].  V: -> [bh][dk][key-permuted s] (swap bit2<->bit3 of s
//        so attention V fragments read as contiguous 16B in crow order).
// EPI 1: out = acc + bias -> fp32 d_out
template<int EPI>
__global__ __launch_bounds__(256)
void k_gemm(const unsigned short* __restrict__ A, const unsigned short* __restrict__ B,
            const float* __restrict__ bias, float* __restrict__ OutF,
            unsigned short* __restrict__ Qb, unsigned short* __restrict__ Kb,
            unsigned short* __restrict__ Vt, int Ntiles, int K) {
    __shared__ __align__(16) unsigned short As[128 * 64];
    __shared__ __align__(16) unsigned short Bs[128 * 64];
    const int t    = threadIdx.x;
    const int lane = t & 63;
    const int wid  = t >> 6;
    const int wm   = (wid >> 1) * 64, wn = (wid & 1) * 64;
    const int bn   = (blockIdx.x % Ntiles) * 128;
    const int bmr  = (blockIdx.x / Ntiles) * 128;
    const int sr   = t >> 3, sc = t & 7;      // staging row / 16B-chunk
    const int l15  = lane & 15, lh = lane >> 4;

    f32x4 acc[4][4];
#pragma unroll
    for (int i = 0; i < 4; ++i)
#pragma unroll
        for (int j = 0; j < 4; ++j)
#pragma unroll
            for (int e = 0; e < 4; ++e) acc[i][j][e] = 0.f;

    for (int k0 = 0; k0 < K; k0 += 64) {
#pragma unroll
        for (int i = 0; i < 4; ++i) {   // stage A tile (pre-swizzled source)
            int r = i * 32 + sr;
            int cs = sc ^ (r & 7);
            gld_lds16(A + ((size_t)(bmr + r) * K + k0 + cs * 8), As + (size_t)t * 8 + i * 2048);
        }
#pragma unroll
        for (int i = 0; i < 4; ++i) {   // stage B tile
            int r = i * 32 + sr;
            int cs = sc ^ (r & 7);
            gld_lds16(B + ((size_t)(bn + r) * K + k0 + cs * 8), Bs + (size_t)t * 8 + i * 2048);
        }
        __syncthreads();
#pragma unroll
        for (int kk = 0; kk < 64; kk += 32) {
            short8 af[4], bf[4];
#pragma unroll
            for (int mi = 0; mi < 4; ++mi) {
                int row = wm + mi * 16 + l15;
                int c = (kk >> 3) + lh;
                af[mi] = *(const short8*)(As + row * 64 + (c ^ (row & 7)) * 8);
            }
#pragma unroll
            for (int ni = 0; ni < 4; ++ni) {
                int row = wn + ni * 16 + l15;
                int c = (kk >> 3) + lh;
                bf[ni] = *(const short8*)(Bs + row * 64 + (c ^ (row & 7)) * 8);
            }
#pragma unroll
            for (int mi = 0; mi < 4; ++mi)
#pragma unroll
                for (int ni = 0; ni < 4; ++ni)
                    acc[mi][ni] = __builtin_amdgcn_mfma_f32_16x16x32_bf16(
                        af[mi], bf[ni], acc[mi][ni], 0, 0, 0);
        }
        __syncthreads();
    }

    const float QS = 0.180336880111f;   // (1/sqrt(64)) * log2(e)
#pragma unroll
    for (int mi = 0; mi < 4; ++mi)
#pragma unroll
        for (int ni = 0; ni < 4; ++ni) {
            int n  = bn + wn + ni * 16 + l15;
            int m0 = bmr + wm + mi * 16 + lh * 4;
            float bv = bias[n];
            if constexpr (EPI == 0) {
                int proj = n >> 10;
                int e = n & 1023;
                int hh = e >> 6, dk = e & 63;
                int b = m0 >> 11, s = m0 & 2047;
                int bh = b * NH + hh;
                if (proj == 2) {          // V -> [bh][dk][perm(s)], 8B packed
                    int sp = (s & ~12) | ((s & 4) << 1) | ((s & 8) >> 1);
                    us4 p;
#pragma unroll
                    for (int j = 0; j < 4; ++j) p[j] = f2bf(acc[mi][ni][j] + bv);
                    *(us4*)(Vt + (size_t)(bh * DKH + dk) * SEQ + sp) = p;
                } else {                  // Q/K -> [bh][s][64]; Q pre-scaled
                    unsigned short* dst = (proj == 0) ? Qb : Kb;
                    float sc2 = (proj == 0) ? QS : 1.f;
#pragma unroll
                    for (int j = 0; j < 4; ++j)
                        dst[((size_t)bh * SEQ + s + j) * DKH + dk] = f2bf((acc[mi][ni][j] + bv) * sc2);
                }
            } else {
#pragma unroll
                for (int j = 0; j < 4; ++j)
                    OutF[(size_t)(m0 + j) * DM + n] = acc[mi][ni][j] + bv;
            }
        }
}

// ---------------- flash attention, 32x32x16 bf16, LDS-staged K/V ----------------
// grid: 1024 blocks (XCD-chunked), 256 threads = 4 waves, 32 q-rows/wave, KVBLK=64.
// K tile (64x64) and V^T tile (64x64) staged via global_load_lds (coalesced,
// shared by all 4 waves), double-buffered, XOR-swizzled (pre-swizzled source).
// Q pre-scaled by (1/sqrt(dk))*log2e; running max folded into MFMA C-init;
// defer-max rescale (THR=8); V key-permuted (done in GEMM epilogue).
__global__ __launch_bounds__(256)
void k_attn(const unsigned short* __restrict__ Qb, const unsigned short* __restrict__ Kb,
            const unsigned short* __restrict__ Vt, unsigned short* __restrict__ Ob) {
    __shared__ __align__(16) unsigned short Ks[2][64 * 64];   // 2 x 8KB
    __shared__ __align__(16) unsigned short Vs[2][64 * 64];   // 2 x 8KB
    const int t = threadIdx.x;
    const int lane = t & 63, w = t >> 6;
    const int g = blockIdx.x;
    const int id = ((g & 7) << 7) | (g >> 3);   // XCD-chunked swizzle (bijective, 1024%8==0)
    const int bh = id >> 4;
    const int qt = id & 15;
    const int q0 = qt * 128 + w * 32;
    const int l31 = lane & 31, hi = lane >> 5;
    const int kch = l31 & 7;                    // row-swizzle class for frag reads

    const unsigned short* Qp = Qb + (size_t)bh * SEQ * DKH;
    const unsigned short* Kp = Kb + (size_t)bh * SEQ * DKH;
    const unsigned short* Vp = Vt + (size_t)bh * DKH * SEQ;

    // staging: thread t covers row sr (and sr+32), pre-swizzled source chunk scs
    const int sr  = t >> 3;
    const int scs = (t & 7) ^ (sr & 7);
    const int sdst = t * 8;                     // shorts; = wave-uniform base + lane*16B

    short8 qf[4];
#pragma unroll
    for (int c = 0; c < 4; ++c)
        qf[c] = *(const short8*)(Qp + (size_t)(q0 + l31) * DKH + c * 16 + hi * 8);

    f32x16 o0, o1;
#pragma unroll
    for (int j = 0; j < 16; ++j) { o0[j] = 0.f; o1[j] = 0.f; }
    float mr = 0.f, lr = 0.f;

    // prologue: stage tile 0 into buffer 0
    gld_lds16(Kp + (size_t)sr * DKH + scs * 8,        &Ks[0][sdst]);
    gld_lds16(Kp + (size_t)(sr + 32) * DKH + scs * 8, &Ks[0][sdst + 2048]);
    gld_lds16(Vp + (size_t)sr * SEQ + scs * 8,        &Vs[0][sdst]);
    gld_lds16(Vp + (size_t)(sr + 32) * SEQ + scs * 8, &Vs[0][sdst + 2048]);
    __syncthreads();

    for (int tt = 0; tt < SEQ / 64; ++tt) {
        const int cur = tt & 1;
        const unsigned short* KsC = Ks[cur];
        const unsigned short* VsC = Vs[cur];
        // prefetch next tile into the other buffer (async; drained by barrier below)
        if (tt + 1 < SEQ / 64) {
            const unsigned short* Kg = Kp + (size_t)(tt + 1) * 64 * DKH;
            const unsigned short* Vg = Vp + (size_t)(tt + 1) * 64;
            unsigned short* KsN = Ks[cur ^ 1];
            unsigned short* VsN = Vs[cur ^ 1];
            gld_lds16(Kg + (size_t)sr * DKH + scs * 8,        KsN + sdst);
            gld_lds16(Kg + (size_t)(sr + 32) * DKH + scs * 8, KsN + sdst + 2048);
            gld_lds16(Vg + (size_t)sr * SEQ + scs * 8,        VsN + sdst);
            gld_lds16(Vg + (size_t)(sr + 32) * SEQ + scs * 8, VsN + sdst + 2048);
        }
        // S^T = K * Q^T with C-init = -m  (=> st holds s - m directly)
        f32x16 st0, st1;
        float nm = -mr;
#pragma unroll
        for (int j = 0; j < 16; ++j) { st0[j] = nm; st1[j] = nm; }
        __builtin_amdgcn_s_setprio(1);
#pragma unroll
        for (int c = 0; c < 4; ++c) {
            short8 kf = *(const short8*)(KsC + l31 * 64 + ((c * 2 + hi) ^ kch) * 8);
            st0 = __builtin_amdgcn_mfma_f32_32x32x16_bf16(kf, qf[c], st0, 0, 0, 0);
        }
#pragma unroll
        for (int c = 0; c < 4; ++c) {
            short8 kf = *(const short8*)(KsC + (l31 + 32) * 64 + ((c * 2 + hi) ^ kch) * 8);
            st1 = __builtin_amdgcn_mfma_f32_32x32x16_bf16(kf, qf[c], st1, 0, 0, 0);
        }
        __builtin_amdgcn_s_setprio(0);
        // V fragment reads issued early (consumed after softmax)
        short8 vf[8];
#pragma unroll
        for (int h = 0; h < 4; ++h) {
            vf[h]     = *(const short8*)(VsC + l31 * 64 + ((h * 2 + hi) ^ kch) * 8);
            vf[4 + h] = *(const short8*)(VsC + (l31 + 32) * 64 + ((h * 2 + hi) ^ kch) * 8);
        }
        // online softmax in exp2 domain, per-lane q = l31 (pair across hi)
        float pm = fmaxf(vmax16(st0), vmax16(st1));
        pm = fmaxf(pm, __shfl_xor(pm, 32));
        if (__any(pm > 8.f)) {            // rare rescale path (defer-max)
            float d   = fmaxf(pm, 0.f);
            float fac = exp2f(-d);
            mr += d;
#pragma unroll
            for (int j = 0; j < 16; ++j) { st0[j] -= d; st1[j] -= d; }
#pragma unroll
            for (int j = 0; j < 16; ++j) { o0[j] *= fac; o1[j] *= fac; }
            lr *= fac;
        }
#pragma unroll
        for (int j = 0; j < 16; ++j) { st0[j] = exp2f(st0[j]); st1[j] = exp2f(st1[j]); }
        float r0 = 0.f, r1 = 0.f, r2 = 0.f, r3 = 0.f;
#pragma unroll
        for (int j = 0; j < 4; ++j) {
            r0 += st0[j] + st0[4 + j];
            r1 += st0[8 + j] + st0[12 + j];
            r2 += st1[j] + st1[4 + j];
            r3 += st1[8 + j] + st1[12 + j];
        }
        float rs = (r0 + r1) + (r2 + r3);
        rs += __shfl_xor(rs, 32);
        lr += rs;
        // pack P fragments (B-operand layout == C-frag reg order, 8 regs per 16-key group)
        short8 p[4];
#pragma unroll
        for (int j = 0; j < 8; ++j) {
            p[0][j] = (short)bfr(st0[j]);
            p[1][j] = (short)bfr(st0[8 + j]);
            p[2][j] = (short)bfr(st1[j]);
            p[3][j] = (short)bfr(st1[8 + j]);
        }
        // PV: O^T += V^T * P^T
        __builtin_amdgcn_s_setprio(1);
#pragma unroll
        for (int h = 0; h < 4; ++h)
            o0 = __builtin_amdgcn_mfma_f32_32x32x16_bf16(vf[h], p[h], o0, 0, 0, 0);
#pragma unroll
        for (int h = 0; h < 4; ++h)
            o1 = __builtin_amdgcn_mfma_f32_32x32x16_bf16(vf[4 + h], p[h], o1, 0, 0, 0);
        __builtin_amdgcn_s_setprio(0);
        __syncthreads();   // drains prefetch (vmcnt) + guards buffer reuse
    }

    float inv = 1.f / lr;
    const int b = bh >> 4, hh = bh & 15;
    size_t tok = (size_t)b * SEQ + q0 + l31;
    unsigned short* Op = Ob + tok * DM + hh * DKH;
#pragma unroll
    for (int gi = 0; gi < 4; ++gi) {
        us4 pa, pb;
#pragma unroll
        for (int j = 0; j < 4; ++j) {
            pa[j] = bfr(o0[4 * gi + j] * inv);
            pb[j] = bfr(o1[4 * gi + j] * inv);
        }
        *(us4*)(Op + 8 * gi + 4 * hi)      = pa;
        *(us4*)(Op + 8 * gi + 4 * hi + 32) = pb;
    }
}

// ---------------- launch ----------------

extern "C" void kernel_launch(void* const* d_in, const int* in_sizes, int n_in,
                              void* d_out, int out_size, void* d_ws, size_t ws_size,
                              hipStream_t stream) {
    const float* x  = (const float*)d_in[0];
    const float* wq = (const float*)d_in[1];
    const float* bq = (const float*)d_in[2];
    const float* wk = (const float*)d_in[3];
    const float* bk = (const float*)d_in[4];
    const float* wv = (const float*)d_in[5];
    const float* bv = (const float*)d_in[6];
    const float* wo = (const float*)d_in[7];
    const float* bo = (const float*)d_in[8];

    char* ws = (char*)d_ws;
    // offsets (bytes). Ob aliases xb (xb dead after QKV GEMM).
    unsigned short* xb   = (unsigned short*)(ws + 0);             // 16 MB
    unsigned short* Wcat = (unsigned short*)(ws + 16777216);      // 6 MB
    unsigned short* Wob  = (unsigned short*)(ws + 23068672);      // 2 MB
    float*          Bcat = (float*)         (ws + 25165824);      // 16 KB pad
    unsigned short* Qb   = (unsigned short*)(ws + 25182208);      // 16 MB
    unsigned short* Kb   = (unsigned short*)(ws + 41959424);      // 16 MB
    unsigned short* Vt   = (unsigned short*)(ws + 58736640);      // 16 MB (total ~72 MB)
    unsigned short* Ob   = xb;

    k_cvt_x <<<MTOK * DM / 1024, 256, 0, stream>>>(x, xb);
    k_pack_w<<<4 * 1024 * 1024 / 1024, 256, 0, stream>>>(wq, wk, wv, wo, Wcat, Wob);
    k_pack_b<<<12, 256, 0, stream>>>(bq, bk, bv, Bcat);
    // QKV: M=8192 (64 tiles), N=3072 (24 tiles), K=1024
    k_gemm<0><<<64 * 24, 256, 0, stream>>>(xb, Wcat, Bcat, nullptr, Qb, Kb, Vt, 24, DM);
    // attention
    k_attn<<<64 * 16, 256, 0, stream>>>(Qb, Kb, Vt, Ob);
    // out projection: M=8192, N=1024 (8 tiles), K=1024 -> fp32 d_out
    k_gemm<1><<<64 * 8, 256, 0, stream>>>(Ob, Wob, bo, (float*)d_out, nullptr, nullptr, nullptr, 8, DM);
}